// Round 8
// baseline (352.916 us; speedup 1.0000x reference)
//
#include <hip/hip_runtime.h>
#include <hip/hip_bf16.h>

#define CCH 256
#define NPIX 4096
#define NB 8
#define LOG2E 1.4426950408889634f

typedef __attribute__((ext_vector_type(8))) short bf16x8;
typedef __attribute__((ext_vector_type(16))) float f32x16;

static __device__ __forceinline__ unsigned pkbf(float a, float b) {
    union { __hip_bfloat16 h[2]; unsigned u; } p;
    p.h[0] = __float2bfloat16(a);
    p.h[1] = __float2bfloat16(b);
    return p.u;
}
static __device__ __forceinline__ unsigned short bf1(float a) {
    union { __hip_bfloat16 h; unsigned short s; } p;
    p.h = __float2bfloat16(a);
    return p.s;
}

// ---------------- Kernel 0: pack W fp32 -> bf16, Wb[320][256] ----------------
__global__ void packw_kernel(const float* __restrict__ Wq,
                             const float* __restrict__ Wk,
                             const float* __restrict__ Wv,
                             unsigned short* __restrict__ Wb) {
    int i4 = blockIdx.x * 256 + threadIdx.x;
    if (i4 >= 20480) return;
    int e = i4 * 4;
    const float* src;
    if (e < 8192)       src = Wq + e;
    else if (e < 16384) src = Wk + (e - 8192);
    else                src = Wv + (e - 16384);
    float4 v = *(const float4*)src;
    uint2 o;
    o.x = pkbf(v.x, v.y);
    o.y = pkbf(v.z, v.w);
    *(uint2*)(Wb + e) = o;
}

// ---------------- Kernel 1: QKV via MFMA, fragment-ordered outputs -----------
// q [B][N][32] bf16 (prescaled log2e), row-major (attn B-operand order).
// k frag layout: flat (px>>5)*1024 + (d>>3)*256 + (px&31)*8 + (d&7)
//   -> attn QK A-frag read (kt,ks32,s,h,lane) is a contiguous 1KB wave-load.
// v frag layout: (kt*64 + cg*8 + chunk)*256 + (c&31)*8 + e, where slot
//   chunk*8+e = swap23(key-local): attn PV A-frag read coalesced, P in-lane.
__global__ __launch_bounds__(320) void qkv_kernel(
    const float* __restrict__ x,
    const unsigned short* __restrict__ Wb,
    const float* __restrict__ bq, const float* __restrict__ bk,
    const float* __restrict__ bv,
    unsigned short* __restrict__ q, unsigned short* __restrict__ k,
    unsigned short* __restrict__ v)
{
    __shared__ __align__(16) unsigned xp[128][36];

    const int t   = threadIdx.x;
    const int b   = blockIdx.x >> 7;
    const int px0 = (blockIdx.x & 127) * 32;

    const float4* gx = (const float4*)x + ((size_t)b * CCH * NPIX + px0) / 4;
    for (int i = t; i < 1024; i += 320) {
        int kp = i >> 3, p4 = i & 7;
        float4 lo = gx[(size_t)(2 * kp) * (NPIX / 4) + p4];
        float4 hi = gx[(size_t)(2 * kp + 1) * (NPIX / 4) + p4];
        uint4 pk4;
        pk4.x = pkbf(lo.x, hi.x);
        pk4.y = pkbf(lo.y, hi.y);
        pk4.z = pkbf(lo.z, hi.z);
        pk4.w = pkbf(lo.w, hi.w);
        *(uint4*)&xp[kp][p4 * 4] = pk4;
    }
    __syncthreads();

    const int w  = t >> 6;
    const int lane = t & 63;
    const int qi = lane & 31, h = lane >> 5;

    f32x16 acc[2];
    #pragma unroll
    for (int rt = 0; rt < 2; ++rt)
        #pragma unroll
        for (int r = 0; r < 16; ++r) acc[rt][r] = 0.f;

    #pragma unroll 4
    for (int ks = 0; ks < 16; ++ks) {
        union { unsigned uw[4]; bf16x8 v8; } xb;
        #pragma unroll
        for (int j = 0; j < 4; ++j) xb.uw[j] = xp[ks * 8 + 4 * h + j][qi];
        #pragma unroll
        for (int rt = 0; rt < 2; ++rt) {
            int row = (2 * w + rt) * 32 + qi;
            bf16x8 af = *(const bf16x8*)(Wb + (size_t)row * 256 + ks * 16 + h * 8);
            acc[rt] = __builtin_amdgcn_mfma_f32_32x32x16_bf16(af, xb.v8, acc[rt], 0, 0, 0);
        }
    }

    const int px = px0 + qi;
    // swap23 of (px&63): bits 2<->3 (bit5 from px0 preserved)
    const int kl = (px0 & 32) | (qi & 19) | ((qi & 4) << 1) | ((qi & 8) >> 1);
    #pragma unroll
    for (int rt = 0; rt < 2; ++rt) {
        int tile = 2 * w + rt;
        if (tile < 2) {
            const float* bias = (tile == 0) ? bq : bk;
            float scale = (tile == 0) ? LOG2E : 1.0f;
            #pragma unroll
            for (int rg = 0; rg < 4; ++rg) {
                float vv[4];
                #pragma unroll
                for (int j = 0; j < 4; ++j) {
                    int outd = j + 8 * rg + 4 * h;
                    vv[j] = (acc[rt][4 * rg + j] + bias[outd]) * scale;
                }
                uint2 st;
                st.x = pkbf(vv[0], vv[1]);
                st.y = pkbf(vv[2], vv[3]);
                if (tile == 0) {   // q: row-major
                    *(uint2*)(q + ((size_t)b * NPIX + px) * 32 + 8 * rg + 4 * h) = st;
                } else {           // k: fragment order, d0 = 8rg+4h
                    *(uint2*)(k + (size_t)b * NPIX * 32 +
                              ((px >> 5) * 4 + rg) * 256 + (px & 31) * 8 + 4 * h) = st;
                }
            }
        } else {                   // v: fragment order, key slot = swap23
            const int cg = tile - 2;
            unsigned short* vb = v + (size_t)b * NPIX * 256 +
                                 ((px >> 6) * 64 + cg * 8 + (kl >> 3) - (px0 & 32)) * 256 +
                                 ((px0 & 32) ? 1024 : 0) + (kl & 7);
            // note: (kl>>3) already includes bit5 (chunk 0..7); rewrite cleanly:
            vb = v + (size_t)b * NPIX * 256 +
                 ((size_t)(px >> 6) * 64 + cg * 8 + ((kl & 63) >> 3)) * 256 + (kl & 7);
            #pragma unroll
            for (int r = 0; r < 16; ++r) {
                int outd = (r & 3) + 8 * (r >> 2) + 4 * h;
                vb[outd * 8] = bf1(acc[rt][r] + bv[cg * 32 + outd]);
            }
        }
    }
}

// ---------------- Kernel 2: barrier-free streaming flash attention -----------
// Block: 512 thr = 8 waves (4 qtiles x 2 ch-halves), 128 queries, grid 256.
// Zero LDS, zero barriers. K/V read as fragments straight from L2 (batch==XCD).
__global__ __launch_bounds__(512, 2) void attn_kernel(
    const unsigned short* __restrict__ qg,
    const unsigned short* __restrict__ kg,
    const unsigned short* __restrict__ vg,
    const float* __restrict__ x,
    const float* __restrict__ gamma,
    float* __restrict__ out)
{
    const int t    = threadIdx.x;
    const int b    = blockIdx.x & 7;          // batch == XCD -> K/V L2-resident
    const int n0   = (blockIdx.x >> 3) * 128;
    const int w    = t >> 6;
    const int lane = t & 63;
    const int qtile = w >> 1, chh = w & 1;
    const int qi = lane & 31, h = lane >> 5;

    bf16x8 qf0, qf1;
    {
        const unsigned short* qp = qg + ((size_t)b * NPIX + n0 + qtile * 32 + qi) * 32;
        qf0 = *(const bf16x8*)(qp + h * 8);
        qf1 = *(const bf16x8*)(qp + 16 + h * 8);
    }

    const unsigned short* kfb = kg + (size_t)b * NPIX * 32 + lane * 8;
    const unsigned short* vfb = vg + (size_t)b * NPIX * 256 + chh * 8192 + h * 256 + qi * 8;

    f32x16 acc[4];
    #pragma unroll
    for (int ct = 0; ct < 4; ++ct)
        #pragma unroll
        for (int r = 0; r < 16; ++r) acc[ct][r] = 0.f;
    f32x16 zero16;
    #pragma unroll
    for (int r = 0; r < 16; ++r) zero16[r] = 0.f;
    float l_run = 0.f;

    for (int kt = 0; kt < 64; ++kt) {
        const unsigned short* kp = kfb + kt * 2048;
        const unsigned short* vp = vfb + (size_t)kt * 16384;

        bf16x8 kf0 = *(const bf16x8*)(kp);
        bf16x8 kf1 = *(const bf16x8*)(kp + 512);
        bf16x8 kf2 = *(const bf16x8*)(kp + 1024);
        bf16x8 kf3 = *(const bf16x8*)(kp + 1536);

        f32x16 s0 = __builtin_amdgcn_mfma_f32_32x32x16_bf16(kf0, qf0, zero16, 0, 0, 0);
        s0 = __builtin_amdgcn_mfma_f32_32x32x16_bf16(kf1, qf1, s0, 0, 0, 0);
        f32x16 s1 = __builtin_amdgcn_mfma_f32_32x32x16_bf16(kf2, qf0, zero16, 0, 0, 0);
        s1 = __builtin_amdgcn_mfma_f32_32x32x16_bf16(kf3, qf1, s1, 0, 0, 0);

        // softmax weights (no-max, q prescaled): pf[s] = exp2(s_{s>>1}[8*(s&1)..+8])
        bf16x8 pf[4];
        #pragma unroll
        for (int sub = 0; sub < 2; ++sub) {
            const f32x16& sv = sub ? s1 : s0;
            #pragma unroll
            for (int sp = 0; sp < 2; ++sp) {
                union { unsigned uw[4]; bf16x8 v8; } pk;
                float ps = 0.f;
                #pragma unroll
                for (int c = 0; c < 4; ++c) {
                    float ea = exp2f(sv[8 * sp + 2 * c]);
                    float eb = exp2f(sv[8 * sp + 2 * c + 1]);
                    ps += ea + eb;
                    pk.uw[c] = pkbf(ea, eb);
                }
                l_run += ps;
                pf[2 * sub + sp] = pk.v8;
            }
        }

        // O^T += V^T · P^T, V A-frags direct from L2
        __builtin_amdgcn_s_setprio(1);
        #pragma unroll
        for (int ct = 0; ct < 4; ++ct) {
            #pragma unroll
            for (int s = 0; s < 4; ++s) {
                bf16x8 vf = *(const bf16x8*)(vp + ct * 2048 + s * 512);
                acc[ct] = __builtin_amdgcn_mfma_f32_32x32x16_bf16(vf, pf[s], acc[ct], 0, 0, 0);
            }
        }
        __builtin_amdgcn_s_setprio(0);
    }

    float l = l_run + __shfl_xor(l_run, 32, 64);
    const float rs = gamma[0] / l;
    #pragma unroll
    for (int ct = 0; ct < 4; ++ct) {
        #pragma unroll
        for (int r = 0; r < 16; ++r) {
            int c = chh * 128 + ct * 32 + (r & 3) + 8 * (r >> 2) + 4 * h;
            size_t off = ((size_t)b * CCH + c) * NPIX + n0 + qtile * 32 + qi;
            out[off] = rs * acc[ct][r] + x[off];
        }
    }
}

extern "C" void kernel_launch(void* const* d_in, const int* in_sizes, int n_in,
                              void* d_out, int out_size, void* d_ws, size_t ws_size,
                              hipStream_t stream) {
    const float* x     = (const float*)d_in[0];
    const float* Wq    = (const float*)d_in[1];
    const float* bq    = (const float*)d_in[2];
    const float* Wk    = (const float*)d_in[3];
    const float* bk    = (const float*)d_in[4];
    const float* Wv    = (const float*)d_in[5];
    const float* bv    = (const float*)d_in[6];
    const float* gamma = (const float*)d_in[7];
    float* out = (float*)d_out;

    unsigned short* Wb = (unsigned short*)d_ws;
    unsigned short* qw = Wb + 320 * 256;
    unsigned short* kw = qw + (size_t)NB * NPIX * 32;
    unsigned short* vw = kw + (size_t)NB * NPIX * 32;

    packw_kernel<<<dim3(80), dim3(256), 0, stream>>>(Wq, Wk, Wv, Wb);
    qkv_kernel<<<dim3(NB * (NPIX / 32)), dim3(320), 0, stream>>>(
        x, Wb, bq, bk, bv, qw, kw, vw);
    attn_kernel<<<dim3(256), dim3(512), 0, stream>>>(
        qw, kw, vw, x, gamma, out);
}

// Round 9
// 162.623 us; speedup vs baseline: 2.1701x; 2.1701x over previous
//
#include <hip/hip_runtime.h>
#include <hip/hip_bf16.h>

#define CCH 256
#define NPIX 4096
#define NB 8
#define LOG2E 1.4426950408889634f

typedef __attribute__((ext_vector_type(8))) short bf16x8;
typedef __attribute__((ext_vector_type(16))) float f32x16;

typedef __attribute__((address_space(3))) unsigned lds_u32;
typedef const __attribute__((address_space(1))) unsigned glb_u32;
#define GL_LDS16(gp, lp) \
    __builtin_amdgcn_global_load_lds((glb_u32*)(gp), (lds_u32*)(lp), 16, 0, 0)

static __device__ __forceinline__ unsigned pkbf(float a, float b) {
    union { __hip_bfloat16 h[2]; unsigned u; } p;
    p.h[0] = __float2bfloat16(a);
    p.h[1] = __float2bfloat16(b);
    return p.u;
}
static __device__ __forceinline__ unsigned short bf1(float a) {
    union { __hip_bfloat16 h; unsigned short s; } p;
    p.h = __float2bfloat16(a);
    return p.s;
}

// ---------------- Kernel 0: pack W fp32 -> bf16, Wb[320][256] ----------------
__global__ void packw_kernel(const float* __restrict__ Wq,
                             const float* __restrict__ Wk,
                             const float* __restrict__ Wv,
                             unsigned short* __restrict__ Wb) {
    int i4 = blockIdx.x * 256 + threadIdx.x;
    if (i4 >= 20480) return;
    int e = i4 * 4;
    const float* src;
    if (e < 8192)       src = Wq + e;
    else if (e < 16384) src = Wk + (e - 8192);
    else                src = Wv + (e - 16384);
    float4 v = *(const float4*)src;
    uint2 o;
    o.x = pkbf(v.x, v.y);
    o.y = pkbf(v.z, v.w);
    *(uint2*)(Wb + e) = o;
}

// ---------------- Kernel 1: QKV via MFMA (r7-proven version) ----------------
// q [B][N][32] bf16 prescaled log2e; k [B][N][32]; v [B][C][N], pixel bit2<->3.
__global__ __launch_bounds__(320) void qkv_kernel(
    const float* __restrict__ x,
    const unsigned short* __restrict__ Wb,
    const float* __restrict__ bq, const float* __restrict__ bk,
    const float* __restrict__ bv,
    unsigned short* __restrict__ q, unsigned short* __restrict__ k,
    unsigned short* __restrict__ v)
{
    __shared__ __align__(16) unsigned xp[128][36];

    const int t   = threadIdx.x;
    const int b   = blockIdx.x >> 7;
    const int px0 = (blockIdx.x & 127) * 32;

    const float4* gx = (const float4*)x + ((size_t)b * CCH * NPIX + px0) / 4;
    for (int i = t; i < 1024; i += 320) {
        int kp = i >> 3, p4 = i & 7;
        float4 lo = gx[(size_t)(2 * kp) * (NPIX / 4) + p4];
        float4 hi = gx[(size_t)(2 * kp + 1) * (NPIX / 4) + p4];
        uint4 pk4;
        pk4.x = pkbf(lo.x, hi.x);
        pk4.y = pkbf(lo.y, hi.y);
        pk4.z = pkbf(lo.z, hi.z);
        pk4.w = pkbf(lo.w, hi.w);
        *(uint4*)&xp[kp][p4 * 4] = pk4;
    }
    __syncthreads();

    const int w  = t >> 6;
    const int lane = t & 63;
    const int qi = lane & 31, h = lane >> 5;

    f32x16 acc[2];
    #pragma unroll
    for (int rt = 0; rt < 2; ++rt)
        #pragma unroll
        for (int r = 0; r < 16; ++r) acc[rt][r] = 0.f;

    #pragma unroll 4
    for (int ks = 0; ks < 16; ++ks) {
        union { unsigned uw[4]; bf16x8 v8; } xb;
        #pragma unroll
        for (int j = 0; j < 4; ++j) xb.uw[j] = xp[ks * 8 + 4 * h + j][qi];
        #pragma unroll
        for (int rt = 0; rt < 2; ++rt) {
            int row = (2 * w + rt) * 32 + qi;
            bf16x8 af = *(const bf16x8*)(Wb + (size_t)row * 256 + ks * 16 + h * 8);
            acc[rt] = __builtin_amdgcn_mfma_f32_32x32x16_bf16(af, xb.v8, acc[rt], 0, 0, 0);
        }
    }

    const int px = px0 + qi;
    const int pxv = px0 + ((qi & 19) | ((qi & 4) << 1) | ((qi & 8) >> 1)); // bits 2<->3
    #pragma unroll
    for (int rt = 0; rt < 2; ++rt) {
        int tile = 2 * w + rt;
        if (tile < 2) {
            const float* bias = (tile == 0) ? bq : bk;
            unsigned short* outp = (tile == 0) ? q : k;
            float scale = (tile == 0) ? LOG2E : 1.0f;
            #pragma unroll
            for (int rg = 0; rg < 4; ++rg) {
                float vv[4];
                #pragma unroll
                for (int j = 0; j < 4; ++j) {
                    int outd = j + 8 * rg + 4 * h;
                    vv[j] = (acc[rt][4 * rg + j] + bias[outd]) * scale;
                }
                uint2 st;
                st.x = pkbf(vv[0], vv[1]);
                st.y = pkbf(vv[2], vv[3]);
                *(uint2*)(outp + ((size_t)b * NPIX + px) * 32 + 8 * rg + 4 * h) = st;
            }
        } else {
            #pragma unroll
            for (int r = 0; r < 16; ++r) {
                int outd = (r & 3) + 8 * (r >> 2) + 4 * h;
                int grow = (tile - 2) * 32 + outd;
                v[((size_t)b * CCH + grow) * NPIX + pxv] = bf1(acc[rt][r] + bv[grow]);
            }
        }
    }
}

// ---------------- Kernel 2: lag-1 pipelined flash attention -------------------
// Block: 256 thr = 4 waves = 4 q-tiles (128 queries) x ONE ch-half (128 ch).
// Grid 512 (8 b x 32 n x 2 chh). K/V triple-buffered via global_load_lds;
// ONE raw barrier + counted vmcnt(4) per 64-key tile; PV lags one tile so
// its 16 MFMA overlap softmax. P in registers (3 rotating static frag sets).
__global__ __launch_bounds__(256, 2) void attn_kernel(
    const unsigned short* __restrict__ qg,
    const unsigned short* __restrict__ kg,
    const unsigned short* __restrict__ vg,
    const float* __restrict__ x,
    const float* __restrict__ gamma,
    float* __restrict__ out)
{
    __shared__ __align__(16) unsigned short Kl[3][64][4][8];   // 12 KB
    __shared__ __align__(16) unsigned short Vl[3][128][8][8];  // 48 KB

    const int t    = threadIdx.x;
    const int b    = blockIdx.x & 7;          // batch == XCD
    const int nc   = blockIdx.x >> 3;
    const int chh  = nc & 1;
    const int n0   = (nc >> 1) * 128;
    const int w    = t >> 6;
    const int lane = t & 63;
    const int qi = lane & 31, h = lane >> 5;

    // Q fragments: q-tile = w
    bf16x8 qf0, qf1;
    {
        const unsigned short* qp = qg + ((size_t)b * NPIX + n0 + w * 32 + qi) * 32;
        qf0 = *(const bf16x8*)(qp + h * 8);
        qf1 = *(const bf16x8*)(qp + 16 + h * 8);
    }

    f32x16 acc[4];
    #pragma unroll
    for (int ct = 0; ct < 4; ++ct)
        #pragma unroll
        for (int r = 0; r < 16; ++r) acc[ct][r] = 0.f;
    float l_run = 0.f;

    // ---- staging sources (swizzle on global source; LDS dest linear) ----
    const int srow = t >> 2;                                   // K row 0..63
    const unsigned short* kg_src =
        kg + ((size_t)b * NPIX + srow) * 32 + ((t & 3) ^ (srow & 3)) * 8;
    const int vrow = t >> 3;                                   // V row 0..31
    const unsigned short* vg_src =
        vg + ((size_t)b * CCH + chh * 128 + vrow) * NPIX + ((t & 7) ^ (vrow & 7)) * 8;
    char* kl_dst = (char*)Kl + t * 16;                         // + buf*4096
    char* vl_dst = (char*)Vl + t * 16;                         // + buf*16384 + p*4096

    // ---- hoisted per-lane LDS read pointers ----
    const unsigned short* krd[2][2];
    #pragma unroll
    for (int sub = 0; sub < 2; ++sub)
        #pragma unroll
        for (int s = 0; s < 2; ++s)
            krd[sub][s] = &Kl[0][sub * 32 + qi][(2 * s + h) ^ (qi & 3)][0];
    const unsigned short* vrd[4];
    #pragma unroll
    for (int s = 0; s < 4; ++s)
        vrd[s] = &Vl[0][qi][(2 * s + h) ^ (qi & 7)][0];

    auto STAGE = [&](int buf, int kt) {        // 5 loads/thread: K first, then V
        const int k0 = kt * 64;
        GL_LDS16(kg_src + (size_t)k0 * 32, kl_dst + buf * 4096);
        #pragma unroll
        for (int p = 0; p < 4; ++p)
            GL_LDS16(vg_src + k0 + (size_t)p * 32 * NPIX,
                     vl_dst + buf * 16384 + p * 4096);
    };

    auto QKSM = [&](int kb, bf16x8* pf) {      // QK^T (64 keys) + softmax -> pf[4]
        f32x16 s0, s1;
        #pragma unroll
        for (int r = 0; r < 16; ++r) { s0[r] = 0.f; s1[r] = 0.f; }
        s0 = __builtin_amdgcn_mfma_f32_32x32x16_bf16(*(const bf16x8*)(krd[0][0] + kb * 2048), qf0, s0, 0, 0, 0);
        s0 = __builtin_amdgcn_mfma_f32_32x32x16_bf16(*(const bf16x8*)(krd[0][1] + kb * 2048), qf1, s0, 0, 0, 0);
        s1 = __builtin_amdgcn_mfma_f32_32x32x16_bf16(*(const bf16x8*)(krd[1][0] + kb * 2048), qf0, s1, 0, 0, 0);
        s1 = __builtin_amdgcn_mfma_f32_32x32x16_bf16(*(const bf16x8*)(krd[1][1] + kb * 2048), qf1, s1, 0, 0, 0);
        #pragma unroll
        for (int sub = 0; sub < 2; ++sub) {
            const f32x16& sv = sub ? s1 : s0;
            #pragma unroll
            for (int sp = 0; sp < 2; ++sp) {
                union { unsigned uw[4]; bf16x8 v8; } pk;
                float ps = 0.f;
                #pragma unroll
                for (int c = 0; c < 4; ++c) {
                    float ea = exp2f(sv[8 * sp + 2 * c]);
                    float eb = exp2f(sv[8 * sp + 2 * c + 1]);
                    ps += ea + eb;
                    pk.uw[c] = pkbf(ea, eb);
                }
                l_run += ps;
                pf[2 * sub + sp] = pk.v8;
            }
        }
    };

    auto PV = [&](int vb, const bf16x8* pf) {  // O^T += V^T P^T (64 keys, 128 ch)
        __builtin_amdgcn_s_setprio(1);
        #pragma unroll
        for (int ct = 0; ct < 4; ++ct) {
            #pragma unroll
            for (int s = 0; s < 4; ++s) {
                bf16x8 vf = *(const bf16x8*)(vrd[s] + vb * 8192 + ct * 2048);
                acc[ct] = __builtin_amdgcn_mfma_f32_32x32x16_bf16(vf, pf[s], acc[ct], 0, 0, 0);
            }
        }
        __builtin_amdgcn_s_setprio(0);
    };

#define VMBAR(N) do { asm volatile("s_waitcnt vmcnt(" #N ")" ::: "memory"); \
                      __builtin_amdgcn_s_barrier(); } while (0)

    bf16x8 pfA[4], pfB[4], pfC[4];

    // prologue
    STAGE(0, 0);
    VMBAR(0);
    // kt = 0 (buf 0): stage tile 1, produce pfA, no PV
    STAGE(1, 1);
    QKSM(0, pfA);
    VMBAR(4);                       // K(1) landed; V(1)x4 in flight

    #pragma unroll 1
    for (int m = 0; m < 20; ++m) {  // kt = 3m+1 .. 3m+3  (1..60)
        STAGE(2, 3 * m + 2); QKSM(1, pfB); PV(0, pfA); VMBAR(4);
        STAGE(0, 3 * m + 3); QKSM(2, pfC); PV(1, pfB); VMBAR(4);
        STAGE(1, 3 * m + 4); QKSM(0, pfA); PV(2, pfC); VMBAR(4);
    }
    // kt = 61, 62, 63 peeled
    STAGE(2, 62); QKSM(1, pfB); PV(0, pfA); VMBAR(4);
    STAGE(0, 63); QKSM(2, pfC); PV(1, pfB); VMBAR(4);
    QKSM(0, pfA); PV(2, pfC);
    VMBAR(0);                       // V(63) landed everywhere
    PV(0, pfA);                     // PV(63)

    // epilogue: out = gamma * O / l + x
    float l = l_run + __shfl_xor(l_run, 32, 64);
    const float rs = gamma[0] / l;
    #pragma unroll
    for (int ct = 0; ct < 4; ++ct) {
        #pragma unroll
        for (int r = 0; r < 16; ++r) {
            int c = chh * 128 + ct * 32 + (r & 3) + 8 * (r >> 2) + 4 * h;
            size_t off = ((size_t)b * CCH + c) * NPIX + n0 + w * 32 + qi;
            out[off] = rs * acc[ct][r] + x[off];
        }
    }
#undef VMBAR
}

extern "C" void kernel_launch(void* const* d_in, const int* in_sizes, int n_in,
                              void* d_out, int out_size, void* d_ws, size_t ws_size,
                              hipStream_t stream) {
    const float* x     = (const float*)d_in[0];
    const float* Wq    = (const float*)d_in[1];
    const float* bq    = (const float*)d_in[2];
    const float* Wk    = (const float*)d_in[3];
    const float* bk    = (const float*)d_in[4];
    const float* Wv    = (const float*)d_in[5];
    const float* bv    = (const float*)d_in[6];
    const float* gamma = (const float*)d_in[7];
    float* out = (float*)d_out;

    unsigned short* Wb = (unsigned short*)d_ws;
    unsigned short* qw = Wb + 320 * 256;
    unsigned short* kw = qw + (size_t)NB * NPIX * 32;
    unsigned short* vw = kw + (size_t)NB * NPIX * 32;

    packw_kernel<<<dim3(80), dim3(256), 0, stream>>>(Wq, Wk, Wv, Wb);
    qkv_kernel<<<dim3(NB * (NPIX / 32)), dim3(320), 0, stream>>>(
        x, Wb, bq, bk, bv, qw, kw, vw);
    attn_kernel<<<dim3(512), dim3(256), 0, stream>>>(
        qw, kw, vw, x, gamma, out);
}

// Round 10
// 142.972 us; speedup vs baseline: 2.4684x; 1.1375x over previous
//
#include <hip/hip_runtime.h>
#include <hip/hip_bf16.h>

#define CCH 256
#define NPIX 4096
#define NB 8
#define LOG2E 1.4426950408889634f

typedef __attribute__((ext_vector_type(8))) short bf16x8;
typedef __attribute__((ext_vector_type(16))) float f32x16;

typedef __attribute__((address_space(3))) unsigned lds_u32;
typedef const __attribute__((address_space(1))) unsigned glb_u32;
#define GL_LDS16(gp, lp) \
    __builtin_amdgcn_global_load_lds((glb_u32*)(gp), (lds_u32*)(lp), 16, 0, 0)

// one barrier per phase; vmcnt/lgkm drained (all in-flight ops issued a full
// compute-phase earlier, so the drain is free)
#define PBAR() do { __builtin_amdgcn_sched_barrier(0); \
    asm volatile("s_waitcnt vmcnt(0) lgkmcnt(0)" ::: "memory"); \
    __builtin_amdgcn_s_barrier(); __builtin_amdgcn_sched_barrier(0); } while (0)

static __device__ __forceinline__ unsigned pkbf(float a, float b) {
    union { __hip_bfloat16 h[2]; unsigned u; } p;
    p.h[0] = __float2bfloat16(a);
    p.h[1] = __float2bfloat16(b);
    return p.u;
}
static __device__ __forceinline__ unsigned short bf1(float a) {
    union { __hip_bfloat16 h; unsigned short s; } p;
    p.h = __float2bfloat16(a);
    return p.s;
}

// ---------------- Kernel 0: pack W fp32 -> bf16, Wb[320][256] ----------------
__global__ void packw_kernel(const float* __restrict__ Wq,
                             const float* __restrict__ Wk,
                             const float* __restrict__ Wv,
                             unsigned short* __restrict__ Wb) {
    int i4 = blockIdx.x * 256 + threadIdx.x;
    if (i4 >= 20480) return;
    int e = i4 * 4;
    const float* src;
    if (e < 8192)       src = Wq + e;
    else if (e < 16384) src = Wk + (e - 8192);
    else                src = Wv + (e - 16384);
    float4 v = *(const float4*)src;
    uint2 o;
    o.x = pkbf(v.x, v.y);
    o.y = pkbf(v.z, v.w);
    *(uint2*)(Wb + e) = o;
}

// ---------------- Kernel 1: QKV via MFMA (r7/r9-proven) ----------------
// q [B][N][32] bf16 prescaled log2e; k [B][N][32]; v [B][C][N], pixel bit2<->3.
__global__ __launch_bounds__(320) void qkv_kernel(
    const float* __restrict__ x,
    const unsigned short* __restrict__ Wb,
    const float* __restrict__ bq, const float* __restrict__ bk,
    const float* __restrict__ bv,
    unsigned short* __restrict__ q, unsigned short* __restrict__ k,
    unsigned short* __restrict__ v)
{
    __shared__ __align__(16) unsigned xp[128][36];

    const int t   = threadIdx.x;
    const int b   = blockIdx.x >> 7;
    const int px0 = (blockIdx.x & 127) * 32;

    const float4* gx = (const float4*)x + ((size_t)b * CCH * NPIX + px0) / 4;
    for (int i = t; i < 1024; i += 320) {
        int kp = i >> 3, p4 = i & 7;
        float4 lo = gx[(size_t)(2 * kp) * (NPIX / 4) + p4];
        float4 hi = gx[(size_t)(2 * kp + 1) * (NPIX / 4) + p4];
        uint4 pk4;
        pk4.x = pkbf(lo.x, hi.x);
        pk4.y = pkbf(lo.y, hi.y);
        pk4.z = pkbf(lo.z, hi.z);
        pk4.w = pkbf(lo.w, hi.w);
        *(uint4*)&xp[kp][p4 * 4] = pk4;
    }
    __syncthreads();

    const int w  = t >> 6;
    const int lane = t & 63;
    const int qi = lane & 31, h = lane >> 5;

    f32x16 acc[2];
    #pragma unroll
    for (int rt = 0; rt < 2; ++rt)
        #pragma unroll
        for (int r = 0; r < 16; ++r) acc[rt][r] = 0.f;

    #pragma unroll 4
    for (int ks = 0; ks < 16; ++ks) {
        union { unsigned uw[4]; bf16x8 v8; } xb;
        #pragma unroll
        for (int j = 0; j < 4; ++j) xb.uw[j] = xp[ks * 8 + 4 * h + j][qi];
        #pragma unroll
        for (int rt = 0; rt < 2; ++rt) {
            int row = (2 * w + rt) * 32 + qi;
            bf16x8 af = *(const bf16x8*)(Wb + (size_t)row * 256 + ks * 16 + h * 8);
            acc[rt] = __builtin_amdgcn_mfma_f32_32x32x16_bf16(af, xb.v8, acc[rt], 0, 0, 0);
        }
    }

    const int px = px0 + qi;
    const int pxv = px0 + ((qi & 19) | ((qi & 4) << 1) | ((qi & 8) >> 1)); // bits 2<->3
    #pragma unroll
    for (int rt = 0; rt < 2; ++rt) {
        int tile = 2 * w + rt;
        if (tile < 2) {
            const float* bias = (tile == 0) ? bq : bk;
            unsigned short* outp = (tile == 0) ? q : k;
            float scale = (tile == 0) ? LOG2E : 1.0f;
            #pragma unroll
            for (int rg = 0; rg < 4; ++rg) {
                float vv[4];
                #pragma unroll
                for (int j = 0; j < 4; ++j) {
                    int outd = j + 8 * rg + 4 * h;
                    vv[j] = (acc[rt][4 * rg + j] + bias[outd]) * scale;
                }
                uint2 st;
                st.x = pkbf(vv[0], vv[1]);
                st.y = pkbf(vv[2], vv[3]);
                *(uint2*)(outp + ((size_t)b * NPIX + px) * 32 + 8 * rg + 4 * h) = st;
            }
        } else {
            #pragma unroll
            for (int r = 0; r < 16; ++r) {
                int outd = (r & 3) + 8 * (r >> 2) + 4 * h;
                int grow = (tile - 2) * 32 + outd;
                v[((size_t)b * CCH + grow) * NPIX + pxv] = bf1(acc[rt][r] + bv[grow]);
            }
        }
    }
}

// ---------------- Kernel 2: producer/consumer flash attention ----------------
// 512 thr, grid 256 (1 block/CU). Waves 0-3: producers (q-tile qt=w): QK^T +
// softmax, P -> LDS transpose Pt. Waves 4-7: consumers (64 ch x 128 q PV).
// Each SIMD hosts 1 producer + 1 consumer -> softmax VALU overlaps PV MFMA.
// One barrier per 64-key tile; K 2-ahead dbuf, V 1-ahead dbuf, P dbuf.
__global__ __launch_bounds__(512, 2) void attn_kernel(
    const unsigned short* __restrict__ qg,
    const unsigned short* __restrict__ kg,
    const unsigned short* __restrict__ vg,
    const float* __restrict__ x,
    const float* __restrict__ gamma,
    float* __restrict__ out)
{
    __shared__ __align__(16) unsigned short Kl[2][64][4][8];    //  8 KB
    __shared__ __align__(16) unsigned short Vl[2][256][8][8];   // 64 KB
    __shared__ __align__(16) unsigned short Pt[2][128][72];     // 36 KB (pad 72)
    __shared__ float Lx[128];

    const int t    = threadIdx.x;
    const int b    = blockIdx.x & 7;          // batch == XCD -> K/V L2-resident
    const int n0   = (blockIdx.x >> 3) * 128;
    const int w    = t >> 6;
    const int lane = t & 63;
    const int qi = lane & 31, h = lane >> 5;

    if (w < 4) {
        // =============== PRODUCER (q-tile qt = w) ===============
        const int qt = w;
        bf16x8 qf0, qf1;
        {
            const unsigned short* qp = qg + ((size_t)b * NPIX + n0 + qt * 32 + qi) * 32;
            qf0 = *(const bf16x8*)(qp + h * 8);
            qf1 = *(const bf16x8*)(qp + 16 + h * 8);
        }
        // K staging: 256 producer threads cover 64 rows x 4 chunks
        const int srow = t >> 2;
        const unsigned short* kg_src =
            kg + ((size_t)b * NPIX + srow) * 32 + ((t & 3) ^ (srow & 3)) * 8;
        char* kl_dst = (char*)Kl + t * 16;
        // K read ptrs (loop-invariant)
        const unsigned short* krd[2][2];
        #pragma unroll
        for (int sub = 0; sub < 2; ++sub)
            #pragma unroll
            for (int s = 0; s < 2; ++s)
                krd[sub][s] = &Kl[0][sub * 32 + qi][(2 * s + h) ^ (qi & 3)][0];
        // P write base: row 32qt+qi, key base 4h (+8m +32sb), u16 units
        unsigned short* pw_base = &Pt[0][32 * qt + qi][4 * h];

        float l_run = 0.f;

        auto STAGEK = [&](int buf, int kt) {
            GL_LDS16(kg_src + (size_t)kt * 2048, kl_dst + buf * 4096);
        };
        auto QKSM = [&](int kt) {
            const int kb = kt & 1;
            f32x16 s0, s1;
            #pragma unroll
            for (int r = 0; r < 16; ++r) { s0[r] = 0.f; s1[r] = 0.f; }
            s0 = __builtin_amdgcn_mfma_f32_32x32x16_bf16(*(const bf16x8*)(krd[0][0] + kb * 2048), qf0, s0, 0, 0, 0);
            s0 = __builtin_amdgcn_mfma_f32_32x32x16_bf16(*(const bf16x8*)(krd[0][1] + kb * 2048), qf1, s0, 0, 0, 0);
            s1 = __builtin_amdgcn_mfma_f32_32x32x16_bf16(*(const bf16x8*)(krd[1][0] + kb * 2048), qf0, s1, 0, 0, 0);
            s1 = __builtin_amdgcn_mfma_f32_32x32x16_bf16(*(const bf16x8*)(krd[1][1] + kb * 2048), qf1, s1, 0, 0, 0);
            unsigned short* pw = pw_base + (kt & 1) * 9216;   // 128*72
            #pragma unroll
            for (int sb = 0; sb < 2; ++sb) {
                const f32x16& sv = sb ? s1 : s0;
                #pragma unroll
                for (int m = 0; m < 4; ++m) {
                    float e0 = exp2f(sv[4 * m + 0]);
                    float e1 = exp2f(sv[4 * m + 1]);
                    float e2 = exp2f(sv[4 * m + 2]);
                    float e3 = exp2f(sv[4 * m + 3]);
                    l_run += (e0 + e1) + (e2 + e3);
                    uint2 val;
                    val.x = pkbf(e0, e1);
                    val.y = pkbf(e2, e3);
                    *(uint2*)(pw + 32 * sb + 8 * m) = val;   // keys 8m+4h+32sb..+3
                }
            }
        };

        STAGEK(0, 0);
        PBAR();                              // phase -2
        QKSM(0);
        STAGEK(1, 1);
        PBAR();                              // phase -1
        #pragma unroll 1
        for (int tt = 0; tt < 64; ++tt) {
            if (tt < 63) {
                QKSM(tt + 1);
                if (tt < 62) STAGEK(tt & 1, tt + 2);
            } else {
                float lt = l_run + __shfl_xor(l_run, 32, 64);
                if (lane < 32) Lx[32 * qt + lane] = lt;
            }
            PBAR();
        }
    } else {
        // =============== CONSUMER (ch-quarter cw = w-4) ===============
        const int cw = w - 4;
        // V staging: wave stages its own 64 ch rows (8 issues x 8 rows)
        const unsigned short* vg_src =
            vg + ((size_t)b * CCH + 64 * cw + (lane >> 3)) * NPIX +
            ((lane & 7) ^ ((lane >> 3) & 7)) * 8;
        char* vl_dst = (char*)Vl + cw * 8192 + lane * 16;
        // V read ptrs
        const unsigned short* vrd[2][4];
        #pragma unroll
        for (int ct = 0; ct < 2; ++ct)
            #pragma unroll
            for (int s = 0; s < 4; ++s)
                vrd[ct][s] = &Vl[0][64 * cw + 32 * ct + qi][(2 * s + h) ^ (qi & 7)][0];
        // P read base: row qi (+32qt), key base 4h (+16s, +8 for hi half)
        const unsigned short* prd = &Pt[0][qi][4 * h];

        f32x16 acc[2][4];
        #pragma unroll
        for (int ct = 0; ct < 2; ++ct)
            #pragma unroll
            for (int qt = 0; qt < 4; ++qt)
                #pragma unroll
                for (int r = 0; r < 16; ++r) acc[ct][qt][r] = 0.f;

        auto STAGEV = [&](int buf, int kt) {
            const unsigned short* s0 = vg_src + kt * 64;
            char* d0 = vl_dst + buf * 32768;
            #pragma unroll
            for (int p = 0; p < 8; ++p)
                GL_LDS16(s0 + (size_t)(8 * p) * NPIX, d0 + p * 1024);
        };
        auto PV = [&](int tt) {
            const int vb = tt & 1;
            bf16x8 vf[2][4];
            #pragma unroll
            for (int ct = 0; ct < 2; ++ct)
                #pragma unroll
                for (int s = 0; s < 4; ++s)
                    vf[ct][s] = *(const bf16x8*)(vrd[ct][s] + vb * 16384);
            const unsigned short* pr0 = prd + (tt & 1) * 9216;
            __builtin_amdgcn_s_setprio(1);
            #pragma unroll
            for (int qt = 0; qt < 4; ++qt) {
                bf16x8 pf[4];
                #pragma unroll
                for (int s = 0; s < 4; ++s) {
                    const unsigned short* pr = pr0 + qt * 2304 + s * 16;
                    uint2 lo = *(const uint2*)(pr);
                    uint2 hi = *(const uint2*)(pr + 8);
                    union { unsigned uw[4]; bf16x8 v8; } pk;
                    pk.uw[0] = lo.x; pk.uw[1] = lo.y;
                    pk.uw[2] = hi.x; pk.uw[3] = hi.y;
                    pf[s] = pk.v8;
                }
                #pragma unroll
                for (int ct = 0; ct < 2; ++ct)
                    #pragma unroll
                    for (int s = 0; s < 4; ++s)
                        acc[ct][qt] = __builtin_amdgcn_mfma_f32_32x32x16_bf16(
                            vf[ct][s], pf[s], acc[ct][qt], 0, 0, 0);
            }
            __builtin_amdgcn_s_setprio(0);
        };

        STAGEV(0, 0);
        PBAR();                              // phase -2
        PBAR();                              // phase -1 (P(0) being produced)
        #pragma unroll 1
        for (int tt = 0; tt < 64; ++tt) {
            if (tt < 63) STAGEV((tt + 1) & 1, tt + 1);
            PV(tt);
            PBAR();
        }

        // epilogue: out = gamma * O / l + x
        const float g = gamma[0];
        float rsl[4];
        #pragma unroll
        for (int qt = 0; qt < 4; ++qt) rsl[qt] = g / Lx[32 * qt + qi];
        #pragma unroll
        for (int ct = 0; ct < 2; ++ct) {
            #pragma unroll
            for (int qt = 0; qt < 4; ++qt) {
                #pragma unroll
                for (int r = 0; r < 16; ++r) {
                    int c = 64 * cw + 32 * ct + (r & 3) + 8 * (r >> 2) + 4 * h;
                    size_t off = ((size_t)b * CCH + c) * NPIX + n0 + 32 * qt + qi;
                    out[off] = rsl[qt] * acc[ct][qt][r] + x[off];
                }
            }
        }
    }
}

extern "C" void kernel_launch(void* const* d_in, const int* in_sizes, int n_in,
                              void* d_out, int out_size, void* d_ws, size_t ws_size,
                              hipStream_t stream) {
    const float* x     = (const float*)d_in[0];
    const float* Wq    = (const float*)d_in[1];
    const float* bq    = (const float*)d_in[2];
    const float* Wk    = (const float*)d_in[3];
    const float* bk    = (const float*)d_in[4];
    const float* Wv    = (const float*)d_in[5];
    const float* bv    = (const float*)d_in[6];
    const float* gamma = (const float*)d_in[7];
    float* out = (float*)d_out;

    unsigned short* Wb = (unsigned short*)d_ws;
    unsigned short* qw = Wb + 320 * 256;
    unsigned short* kw = qw + (size_t)NB * NPIX * 32;
    unsigned short* vw = kw + (size_t)NB * NPIX * 32;

    packw_kernel<<<dim3(80), dim3(256), 0, stream>>>(Wq, Wk, Wv, Wb);
    qkv_kernel<<<dim3(NB * (NPIX / 32)), dim3(320), 0, stream>>>(
        x, Wb, bq, bk, bv, qw, kw, vw);
    attn_kernel<<<dim3(256), dim3(512), 0, stream>>>(
        qw, kw, vw, x, gamma, out);
}

// Round 11
// 141.627 us; speedup vs baseline: 2.4919x; 1.0095x over previous
//
#include <hip/hip_runtime.h>
#include <hip/hip_bf16.h>

#define CCH 256
#define NPIX 4096
#define NB 8
#define LOG2E 1.4426950408889634f

typedef __attribute__((ext_vector_type(8))) short bf16x8;
typedef __attribute__((ext_vector_type(16))) float f32x16;

typedef __attribute__((address_space(3))) unsigned lds_u32;
typedef const __attribute__((address_space(1))) unsigned glb_u32;
#define GL_LDS16(gp, lp) \
    __builtin_amdgcn_global_load_lds((glb_u32*)(gp), (lds_u32*)(lp), 16, 0, 0)

// one barrier per phase; producers drain their own staging (a full tile old),
// consumers have no vmem -> drain free
#define PBAR() do { __builtin_amdgcn_sched_barrier(0); \
    asm volatile("s_waitcnt vmcnt(0) lgkmcnt(0)" ::: "memory"); \
    __builtin_amdgcn_s_barrier(); __builtin_amdgcn_sched_barrier(0); } while (0)

static __device__ __forceinline__ unsigned pkbf(float a, float b) {
    union { __hip_bfloat16 h[2]; unsigned u; } p;
    p.h[0] = __float2bfloat16(a);
    p.h[1] = __float2bfloat16(b);
    return p.u;
}
static __device__ __forceinline__ unsigned short bf1(float a) {
    union { __hip_bfloat16 h; unsigned short s; } p;
    p.h = __float2bfloat16(a);
    return p.s;
}

// ---------------- Kernel 0: pack W fp32 -> bf16, Wb[320][256] ----------------
__global__ void packw_kernel(const float* __restrict__ Wq,
                             const float* __restrict__ Wk,
                             const float* __restrict__ Wv,
                             unsigned short* __restrict__ Wb) {
    int i4 = blockIdx.x * 256 + threadIdx.x;
    if (i4 >= 20480) return;
    int e = i4 * 4;
    const float* src;
    if (e < 8192)       src = Wq + e;
    else if (e < 16384) src = Wk + (e - 8192);
    else                src = Wv + (e - 16384);
    float4 v = *(const float4*)src;
    uint2 o;
    o.x = pkbf(v.x, v.y);
    o.y = pkbf(v.z, v.w);
    *(uint2*)(Wb + e) = o;
}

// ---------------- Kernel 1: QKV via MFMA (r7/r9-proven) ----------------
// q [B][N][32] bf16 prescaled log2e; k [B][N][32]; v [B][C][N], pixel bit2<->3.
__global__ __launch_bounds__(320) void qkv_kernel(
    const float* __restrict__ x,
    const unsigned short* __restrict__ Wb,
    const float* __restrict__ bq, const float* __restrict__ bk,
    const float* __restrict__ bv,
    unsigned short* __restrict__ q, unsigned short* __restrict__ k,
    unsigned short* __restrict__ v)
{
    __shared__ __align__(16) unsigned xp[128][36];

    const int t   = threadIdx.x;
    const int b   = blockIdx.x >> 7;
    const int px0 = (blockIdx.x & 127) * 32;

    const float4* gx = (const float4*)x + ((size_t)b * CCH * NPIX + px0) / 4;
    for (int i = t; i < 1024; i += 320) {
        int kp = i >> 3, p4 = i & 7;
        float4 lo = gx[(size_t)(2 * kp) * (NPIX / 4) + p4];
        float4 hi = gx[(size_t)(2 * kp + 1) * (NPIX / 4) + p4];
        uint4 pk4;
        pk4.x = pkbf(lo.x, hi.x);
        pk4.y = pkbf(lo.y, hi.y);
        pk4.z = pkbf(lo.z, hi.z);
        pk4.w = pkbf(lo.w, hi.w);
        *(uint4*)&xp[kp][p4 * 4] = pk4;
    }
    __syncthreads();

    const int w  = t >> 6;
    const int lane = t & 63;
    const int qi = lane & 31, h = lane >> 5;

    f32x16 acc[2];
    #pragma unroll
    for (int rt = 0; rt < 2; ++rt)
        #pragma unroll
        for (int r = 0; r < 16; ++r) acc[rt][r] = 0.f;

    #pragma unroll 4
    for (int ks = 0; ks < 16; ++ks) {
        union { unsigned uw[4]; bf16x8 v8; } xb;
        #pragma unroll
        for (int j = 0; j < 4; ++j) xb.uw[j] = xp[ks * 8 + 4 * h + j][qi];
        #pragma unroll
        for (int rt = 0; rt < 2; ++rt) {
            int row = (2 * w + rt) * 32 + qi;
            bf16x8 af = *(const bf16x8*)(Wb + (size_t)row * 256 + ks * 16 + h * 8);
            acc[rt] = __builtin_amdgcn_mfma_f32_32x32x16_bf16(af, xb.v8, acc[rt], 0, 0, 0);
        }
    }

    const int px = px0 + qi;
    const int pxv = px0 + ((qi & 19) | ((qi & 4) << 1) | ((qi & 8) >> 1)); // bits 2<->3
    #pragma unroll
    for (int rt = 0; rt < 2; ++rt) {
        int tile = 2 * w + rt;
        if (tile < 2) {
            const float* bias = (tile == 0) ? bq : bk;
            unsigned short* outp = (tile == 0) ? q : k;
            float scale = (tile == 0) ? LOG2E : 1.0f;
            #pragma unroll
            for (int rg = 0; rg < 4; ++rg) {
                float vv[4];
                #pragma unroll
                for (int j = 0; j < 4; ++j) {
                    int outd = j + 8 * rg + 4 * h;
                    vv[j] = (acc[rt][4 * rg + j] + bias[outd]) * scale;
                }
                uint2 st;
                st.x = pkbf(vv[0], vv[1]);
                st.y = pkbf(vv[2], vv[3]);
                *(uint2*)(outp + ((size_t)b * NPIX + px) * 32 + 8 * rg + 4 * h) = st;
            }
        } else {
            #pragma unroll
            for (int r = 0; r < 16; ++r) {
                int outd = (r & 3) + 8 * (r >> 2) + 4 * h;
                int grow = (tile - 2) * 32 + outd;
                v[((size_t)b * CCH + grow) * NPIX + pxv] = bf1(acc[rt][r] + bv[grow]);
            }
        }
    }
}

// ---------------- Kernel 2: producer/consumer flash attention ----------------
// 512 thr, grid 256 (1 block/CU). Waves 0-3: producers (q-tile qt=w): ALL K/V
// staging + QK^T + softmax -> Pt (b128, slot-XOR, conflict-free). Waves 4-7:
// consumers (64ch x 128q PV), pure LDS+MFMA. One barrier per 64-key tile.
__global__ __launch_bounds__(512, 2) void attn_kernel(
    const unsigned short* __restrict__ qg,
    const unsigned short* __restrict__ kg,
    const unsigned short* __restrict__ vg,
    const float* __restrict__ x,
    const float* __restrict__ gamma,
    float* __restrict__ out)
{
    __shared__ __align__(16) unsigned short Kl[2][64][4][8];    //  8 KB
    __shared__ __align__(16) unsigned short Vl[2][256][8][8];   // 64 KB
    __shared__ __align__(16) unsigned short Pt[2][128][64];     // 32 KB
    __shared__ float Lx[128];

    const int t    = threadIdx.x;
    const int b    = blockIdx.x & 7;          // batch == XCD -> K/V L2-resident
    const int n0   = (blockIdx.x >> 3) * 128;
    const int w    = t >> 6;
    const int lane = t & 63;
    const int qi = lane & 31, h = lane >> 5;

    // fragment slot offsets (shorts), shared formula producer/consumer:
    // slot(s) = (2s+h) ^ (qi&7); fragment holds keys 16s+8a+4h+j at elem 4a+j
    int po[4];
    #pragma unroll
    for (int s = 0; s < 4; ++s) po[s] = ((2 * s + h) ^ (qi & 7)) * 8;

    if (w < 4) {
        // =============== PRODUCER (q-tile qt = w) ===============
        const int qt = w;
        bf16x8 qf0, qf1;
        {
            const unsigned short* qp = qg + ((size_t)b * NPIX + n0 + qt * 32 + qi) * 32;
            qf0 = *(const bf16x8*)(qp + h * 8);
            qf1 = *(const bf16x8*)(qp + 16 + h * 8);
        }
        // staging sources (256 producer threads; swizzle on global source)
        const int srow = t >> 2;                                  // K row 0..63
        const unsigned short* kg_src =
            kg + ((size_t)b * NPIX + srow) * 32 + ((t & 3) ^ (srow & 3)) * 8;
        const int vrow = t >> 3;                                  // V row 0..31
        const unsigned short* vg_src =
            vg + ((size_t)b * CCH + vrow) * NPIX + ((t & 7) ^ (vrow & 7)) * 8;
        char* kl_dst = (char*)Kl + t * 16;                        // + kbuf*4096
        char* vl_dst = (char*)Vl + t * 16;                        // + vbuf*32768 + p*4096

        // K read ptrs (loop-invariant)
        const unsigned short* krd[2][2];
        #pragma unroll
        for (int sub = 0; sub < 2; ++sub)
            #pragma unroll
            for (int s = 0; s < 2; ++s)
                krd[sub][s] = &Kl[0][sub * 32 + qi][(2 * s + h) ^ (qi & 3)][0];
        // P write base (row 32qt+qi)
        unsigned short* pw = &Pt[0][32 * qt + qi][0];

        float l_run = 0.f;

        auto STAGEV = [&](int kt) {           // V(kt) -> Vl[kt&1], 8 loads
            const unsigned short* s0 = vg_src + kt * 64;
            char* d0 = vl_dst + (kt & 1) * 32768;
            #pragma unroll
            for (int p = 0; p < 8; ++p)
                GL_LDS16(s0 + (size_t)(32 * p) * NPIX, d0 + p * 4096);
        };
        auto STAGEK = [&](int kt) {           // K(kt) -> Kl[kt&1], 1 load
            GL_LDS16(kg_src + (size_t)kt * 2048, kl_dst + (kt & 1) * 4096);
        };
        auto QKSM = [&](int kt) {             // QK^T(64 keys) + softmax -> Pt[kt&1]
            const int kb = (kt & 1) * 2048;   // shorts
            f32x16 s0, s1;
            #pragma unroll
            for (int r = 0; r < 16; ++r) { s0[r] = 0.f; s1[r] = 0.f; }
            s0 = __builtin_amdgcn_mfma_f32_32x32x16_bf16(*(const bf16x8*)(krd[0][0] + kb), qf0, s0, 0, 0, 0);
            s0 = __builtin_amdgcn_mfma_f32_32x32x16_bf16(*(const bf16x8*)(krd[0][1] + kb), qf1, s0, 0, 0, 0);
            s1 = __builtin_amdgcn_mfma_f32_32x32x16_bf16(*(const bf16x8*)(krd[1][0] + kb), qf0, s1, 0, 0, 0);
            s1 = __builtin_amdgcn_mfma_f32_32x32x16_bf16(*(const bf16x8*)(krd[1][1] + kb), qf1, s1, 0, 0, 0);
            unsigned short* pwb = pw + (kt & 1) * 8192;
            #pragma unroll
            for (int sub = 0; sub < 2; ++sub) {
                const f32x16& sv = sub ? s1 : s0;
                #pragma unroll
                for (int mh = 0; mh < 2; ++mh) {
                    union { unsigned uw[4]; bf16x8 v8; } pk;
                    float ps = 0.f;
                    #pragma unroll
                    for (int c = 0; c < 4; ++c) {
                        float ea = exp2f(sv[8 * mh + 2 * c]);
                        float eb = exp2f(sv[8 * mh + 2 * c + 1]);
                        ps += ea + eb;
                        pk.uw[c] = pkbf(ea, eb);
                    }
                    l_run += ps;
                    *(bf16x8*)(pwb + po[2 * sub + mh]) = pk.v8;   // b128, conflict-free
                }
            }
        };

        // prologue: V(0), K(0), K(1)
        STAGEV(0);
        STAGEK(0);
        STAGEK(1);
        PBAR();
        QKSM(0);                             // Pt[0] ready after next PBAR
        PBAR();
        #pragma unroll 1
        for (int tt = 0; tt < 64; ++tt) {
            if (tt < 63) {
                STAGEV(tt + 1);              // -> Vl[(tt+1)&1] (read next tile)
                if (tt < 62) STAGEK(tt + 2); // -> Kl[tt&1]     (read next tile)
                QKSM(tt + 1);                // reads Kl[(tt+1)&1], writes Pt[(tt+1)&1]
            } else {
                float lt = l_run + __shfl_xor(l_run, 32, 64);
                if (lane < 32) Lx[32 * qt + lane] = lt;
            }
            PBAR();
        }
    } else {
        // =============== CONSUMER (ch-quarter cw = w-4), pure LDS+MFMA ========
        const int cw = w - 4;
        const unsigned short* vrd[2][4];
        #pragma unroll
        for (int ct = 0; ct < 2; ++ct)
            #pragma unroll
            for (int s = 0; s < 4; ++s)
                vrd[ct][s] = &Vl[0][64 * cw + 32 * ct + qi][(2 * s + h) ^ (qi & 7)][0];
        const unsigned short* prd = &Pt[0][qi][0];

        f32x16 acc[2][4];
        #pragma unroll
        for (int ct = 0; ct < 2; ++ct)
            #pragma unroll
            for (int qt = 0; qt < 4; ++qt)
                #pragma unroll
                for (int r = 0; r < 16; ++r) acc[ct][qt][r] = 0.f;

        PBAR();                              // matches producer prologue
        PBAR();
        #pragma unroll 1
        for (int tt = 0; tt < 64; ++tt) {
            const int vb = (tt & 1) * 16384;  // shorts
            const int pb = (tt & 1) * 8192;   // shorts
            bf16x8 vf[2][4];
            #pragma unroll
            for (int ct = 0; ct < 2; ++ct)
                #pragma unroll
                for (int s = 0; s < 4; ++s)
                    vf[ct][s] = *(const bf16x8*)(vrd[ct][s] + vb);
            __builtin_amdgcn_s_setprio(1);
            #pragma unroll
            for (int qt = 0; qt < 4; ++qt) {
                bf16x8 pf[4];
                #pragma unroll
                for (int s = 0; s < 4; ++s)
                    pf[s] = *(const bf16x8*)(prd + pb + qt * 2048 + po[s]);
                #pragma unroll
                for (int ct = 0; ct < 2; ++ct)
                    #pragma unroll
                    for (int s = 0; s < 4; ++s)
                        acc[ct][qt] = __builtin_amdgcn_mfma_f32_32x32x16_bf16(
                            vf[ct][s], pf[s], acc[ct][qt], 0, 0, 0);
            }
            __builtin_amdgcn_s_setprio(0);
            PBAR();
        }

        // epilogue: out = gamma * O / l + x
        const float g = gamma[0];
        float rsl[4];
        #pragma unroll
        for (int qt = 0; qt < 4; ++qt) rsl[qt] = g / Lx[32 * qt + qi];
        #pragma unroll
        for (int ct = 0; ct < 2; ++ct) {
            #pragma unroll
            for (int qt = 0; qt < 4; ++qt) {
                #pragma unroll
                for (int r = 0; r < 16; ++r) {
                    int c = 64 * cw + 32 * ct + (r & 3) + 8 * (r >> 2) + 4 * h;
                    size_t off = ((size_t)b * CCH + c) * NPIX + n0 + 32 * qt + qi;
                    out[off] = rsl[qt] * acc[ct][qt][r] + x[off];
                }
            }
        }
    }
}

extern "C" void kernel_launch(void* const* d_in, const int* in_sizes, int n_in,
                              void* d_out, int out_size, void* d_ws, size_t ws_size,
                              hipStream_t stream) {
    const float* x     = (const float*)d_in[0];
    const float* Wq    = (const float*)d_in[1];
    const float* bq    = (const float*)d_in[2];
    const float* Wk    = (const float*)d_in[3];
    const float* bk    = (const float*)d_in[4];
    const float* Wv    = (const float*)d_in[5];
    const float* bv    = (const float*)d_in[6];
    const float* gamma = (const float*)d_in[7];
    float* out = (float*)d_out;

    unsigned short* Wb = (unsigned short*)d_ws;
    unsigned short* qw = Wb + 320 * 256;
    unsigned short* kw = qw + (size_t)NB * NPIX * 32;
    unsigned short* vw = kw + (size_t)NB * NPIX * 32;

    packw_kernel<<<dim3(80), dim3(256), 0, stream>>>(Wq, Wk, Wv, Wb);
    qkv_kernel<<<dim3(NB * (NPIX / 32)), dim3(320), 0, stream>>>(
        x, Wb, bq, bk, bv, qw, kw, vw);
    attn_kernel<<<dim3(256), dim3(512), 0, stream>>>(
        qw, kw, vw, x, gamma, out);
}